// Round 1
// baseline (42817.502 us; speedup 1.0000x reference)
//
#include <hip/hip_runtime.h>
#include <stdint.h>

#define NNODES 2048
#define T_SEQ  2048
#define HD     640
#define GD     2560   // 4*HD
#define KIN    8500
#define NEDGE  65536
#define NGRAPH 16

// ---------------------------------------------------------------------------
// Generic C[M,N] = A[M,K] @ W[N,K]^T + b1[n] + b2[n]   (fp32, 64x64x16 tile)
// ---------------------------------------------------------------------------
__global__ __launch_bounds__(256) void gemm_abt(
    const float* __restrict__ A, const float* __restrict__ W,
    const float* __restrict__ b1, const float* __restrict__ b2,
    float* __restrict__ C, int M, int N, int K) {
  __shared__ float As[16][64];
  __shared__ float Ws[16][64];
  const int tid = threadIdx.x;
  const int bm = blockIdx.y * 64, bn = blockIdx.x * 64;
  const int lr = tid >> 2;          // 0..63: row within tile
  const int lc4 = (tid & 3) << 2;   // 0,4,8,12: k offset
  const int ty = tid >> 4, tx = tid & 15;
  float acc[4][4] = {};
  const long lK = K;
  for (int k0 = 0; k0 < K; k0 += 16) {
    float a0=0.f,a1=0.f,a2=0.f,a3=0.f, w0=0.f,w1=0.f,w2=0.f,w3=0.f;
    const int ka = k0 + lc4;
    const float* Ap = A + (long)(bm + lr) * lK;
    const float* Wp = W + (long)(bn + lr) * lK;
    if (ka + 3 < K) {
      float4 av = *(const float4*)(Ap + ka);
      float4 wv = *(const float4*)(Wp + ka);
      a0=av.x; a1=av.y; a2=av.z; a3=av.w;
      w0=wv.x; w1=wv.y; w2=wv.z; w3=wv.w;
    } else {
      if (ka     < K) { a0 = Ap[ka];   w0 = Wp[ka];   }
      if (ka + 1 < K) { a1 = Ap[ka+1]; w1 = Wp[ka+1]; }
      if (ka + 2 < K) { a2 = Ap[ka+2]; w2 = Wp[ka+2]; }
    }
    __syncthreads();
    As[lc4+0][lr]=a0; As[lc4+1][lr]=a1; As[lc4+2][lr]=a2; As[lc4+3][lr]=a3;
    Ws[lc4+0][lr]=w0; Ws[lc4+1][lr]=w1; Ws[lc4+2][lr]=w2; Ws[lc4+3][lr]=w3;
    __syncthreads();
#pragma unroll
    for (int kk = 0; kk < 16; kk++) {
      float4 a4 = *(const float4*)&As[kk][ty<<2];
      float4 w4 = *(const float4*)&Ws[kk][tx<<2];
      float avv[4] = {a4.x,a4.y,a4.z,a4.w};
      float wvv[4] = {w4.x,w4.y,w4.z,w4.w};
#pragma unroll
      for (int i = 0; i < 4; i++)
#pragma unroll
        for (int j = 0; j < 4; j++)
          acc[i][j] = fmaf(avv[i], wvv[j], acc[i][j]);
    }
  }
#pragma unroll
  for (int i = 0; i < 4; i++) {
    const int m = bm + (ty<<2) + i;
#pragma unroll
    for (int j = 0; j < 4; j++) {
      const int n = bn + (tx<<2) + j;
      C[(long)m * N + n] = acc[i][j] + b1[n] + b2[n];
    }
  }
}

// ---------------------------------------------------------------------------
// Persistent LSTM scan. 64 blocks x 256 thr; block b owns h-dims [b*10, b*10+10).
// W_hh slice (40 gate rows x 640) lives in LDS as packed bf16 pairs (51.2 KB).
// Cross-block per-step sync: release/acquire counter at AGENT scope.
// ---------------------------------------------------------------------------
#define SB  64
#define SDP 10   // dims per block

__device__ __forceinline__ unsigned int f2bf(float x) {
  unsigned int u = __float_as_uint(x);
  return (u + 0x7fffu + ((u >> 16) & 1u)) >> 16;
}

__global__ __launch_bounds__(256, 1) void lstm_scan(
    const float* __restrict__ xp,    // [T, 2560] precomputed input projections (+biases)
    const float* __restrict__ whh,   // [2560, 640]
    float* __restrict__ hs,          // [T, 640]  published h sequence (output)
    unsigned int* cnt) {             // [T] step counters (zeroed)
  __shared__ unsigned int wlds[40 * 320];  // 40 rows x 320 bf16-pairs
  __shared__ float gdot[40];
  const int tid = threadIdx.x, b = blockIdx.x;
  const int lane = tid & 63, wv = tid >> 6;   // wave == gate index

  // stage W_hh slice -> LDS bf16
  for (int idx = tid; idx < 40 * 320; idx += 256) {
    const int r = idx / 320, p = idx - r * 320;
    const int g = r / SDP, d = r - g * SDP;
    const int grow = g * HD + b * SDP + d;
    const float2 wpair = *(const float2*)(whh + (long)grow * HD + 2 * p);
    wlds[idx] = f2bf(wpair.x) | (f2bf(wpair.y) << 16);
  }
  __syncthreads();

  float creg = 0.f;  // cell state for thread tid < SDP
  for (int t = 0; t < T_SEQ; t++) {
    if (t > 0) {
      if (tid == 0) {
        long spins = 0;
        while (__hip_atomic_load(cnt + (t - 1), __ATOMIC_RELAXED,
                                 __HIP_MEMORY_SCOPE_AGENT) < (unsigned)SB) {
          if (++spins > (long)50000000) break;  // safety: wrong > hung
        }
        (void)__hip_atomic_load(cnt + (t - 1), __ATOMIC_ACQUIRE,
                                __HIP_MEMORY_SCOPE_AGENT);
      }
      __syncthreads();
      // load h_{t-1}: lane holds pairs h[2*lane+128m], h[2*lane+1+128m]
      const float2* hrow = (const float2*)(hs + (long)(t - 1) * HD);
      float2 hv[5];
#pragma unroll
      for (int m = 0; m < 5; m++) hv[m] = hrow[lane + 64 * m];
      // dot products: wave wv handles its gate's 10 rows
#pragma unroll
      for (int d = 0; d < SDP; d++) {
        const unsigned int* wrow = &wlds[(wv * SDP + d) * 320];
        float p = 0.f;
#pragma unroll
        for (int m = 0; m < 5; m++) {
          const unsigned int u = wrow[lane + 64 * m];
          const float lo = __uint_as_float(u << 16);
          const float hi = __uint_as_float(u & 0xffff0000u);
          p = fmaf(hv[m].x, lo, p);
          p = fmaf(hv[m].y, hi, p);
        }
#pragma unroll
        for (int off = 32; off; off >>= 1) p += __shfl_down(p, off, 64);
        if (lane == 0) gdot[wv * SDP + d] = p;
      }
    }
    __syncthreads();
    if (tid < SDP) {
      const int j = b * SDP + tid;
      const float* xr = xp + (long)t * GD;
      float gi = xr[j], gf = xr[HD + j], gg = xr[2 * HD + j], go = xr[3 * HD + j];
      if (t > 0) {
        gi += gdot[tid];       gf += gdot[SDP + tid];
        gg += gdot[2*SDP + tid]; go += gdot[3*SDP + tid];
      }
      const float si = 1.f / (1.f + expf(-gi));
      const float sf = 1.f / (1.f + expf(-gf));
      const float so = 1.f / (1.f + expf(-go));
      creg = sf * creg + si * tanhf(gg);
      hs[(long)t * HD + j] = so * tanhf(creg);
    }
    __syncthreads();  // drains vm stores before the release below
    if (tid == 0)
      __hip_atomic_fetch_add(cnt + t, 1u, __ATOMIC_RELEASE,
                             __HIP_MEMORY_SCOPE_AGENT);
  }
}

// ---------------------------------------------------------------------------
// GCN pieces
// ---------------------------------------------------------------------------
__global__ __launch_bounds__(256) void gcn_gemm(      // Y[N,do] = X[N,di] @ W[di,do]
    const float* __restrict__ X, const float* __restrict__ W,
    float* __restrict__ Y, int di, int dout) {
  __shared__ float xr[640];
  const int n = blockIdx.x;
  for (int k = threadIdx.x; k < di; k += 256) xr[k] = X[(long)n * di + k];
  __syncthreads();
  for (int c = threadIdx.x; c < dout; c += 256) {
    float acc = 0.f;
    for (int k = 0; k < di; k++) acc = fmaf(xr[k], W[(long)k * dout + c], acc);
    Y[(long)n * dout + c] = acc;
  }
}

__global__ void deg_kernel(const int* __restrict__ dst, unsigned int* __restrict__ deg) {
  const int e = blockIdx.x * 256 + threadIdx.x;
  if (e < NEDGE) atomicAdd(&deg[dst[e]], 1u);
}

__global__ void dinv_kernel(const unsigned int* __restrict__ deg, float* __restrict__ dinv) {
  const int n = blockIdx.x * 256 + threadIdx.x;
  if (n < NNODES) dinv[n] = 1.f / sqrtf((float)(deg[n] + 1u));  // +1 self-loop
}

__global__ __launch_bounds__(128) void gcn_scatter(
    const float* __restrict__ XW, const int* __restrict__ src,
    const int* __restrict__ dst, const float* __restrict__ dinv,
    float* __restrict__ out, int dout) {
  const int e = blockIdx.x;
  const int s = src[e], d = dst[e];
  const float nrm = dinv[s] * dinv[d];
  for (int c = threadIdx.x; c < dout; c += 128)
    atomicAdd(&out[(long)d * dout + c], XW[(long)s * dout + c] * nrm);
}

// bias + self-loop + LeakyReLU + BatchNorm (biased var, eps 1e-5), one channel/block
__global__ __launch_bounds__(256) void gcn_bn(
    const float* __restrict__ scat, const float* __restrict__ xw,
    const float* __restrict__ dinv, const float* __restrict__ bias,
    float* __restrict__ out, int dout) {
  const int c = blockIdx.x;
  const float bc = bias[c];
  float s = 0.f, s2 = 0.f;
  for (int n = threadIdx.x; n < NNODES; n += 256) {
    float v = scat[(long)n * dout + c] + xw[(long)n * dout + c] * dinv[n] * dinv[n] + bc;
    v = v >= 0.f ? v : 0.01f * v;
    s += v; s2 += v * v;
  }
  __shared__ float rs[4], rs2[4];
#pragma unroll
  for (int off = 32; off; off >>= 1) { s += __shfl_down(s, off, 64); s2 += __shfl_down(s2, off, 64); }
  const int w = threadIdx.x >> 6;
  if ((threadIdx.x & 63) == 0) { rs[w] = s; rs2[w] = s2; }
  __syncthreads();
  const float ts  = rs[0] + rs[1] + rs[2] + rs[3];
  const float ts2 = rs2[0] + rs2[1] + rs2[2] + rs2[3];
  const float mu = ts * (1.f / (float)NNODES);
  const float var = ts2 * (1.f / (float)NNODES) - mu * mu;
  const float rstd = 1.f / sqrtf(var + 1e-5f);
  for (int n = threadIdx.x; n < NNODES; n += 256) {
    float v = scat[(long)n * dout + c] + xw[(long)n * dout + c] * dinv[n] * dinv[n] + bc;
    v = v >= 0.f ? v : 0.01f * v;
    out[(long)n * dout + c] = (v - mu) * rstd;
  }
}

// ---------------------------------------------------------------------------
// pool + FC head
// ---------------------------------------------------------------------------
__global__ __launch_bounds__(64) void pool_kernel(
    const float* __restrict__ x, float* __restrict__ emb, float* __restrict__ dout) {
  const int g = blockIdx.x, c = threadIdx.x;
  if (c >= 50) return;
  float s = 0.f;
  for (int r = 0; r < 128; r++) s += x[(long)(g * 128 + r) * 50 + c];
  emb[g * 50 + c] = s;
  dout[16 + g * 50 + c] = s;
}

__global__ __launch_bounds__(64) void fc_head(
    const float* __restrict__ emb,
    const float* __restrict__ w1, const float* __restrict__ b1,
    const float* __restrict__ w2, const float* __restrict__ b2,
    const float* __restrict__ w3, const float* __restrict__ b3,
    float* __restrict__ dout) {
  const int g = threadIdx.x;
  if (g >= NGRAPH) return;
  float e[50];
#pragma unroll
  for (int k = 0; k < 50; k++) e[k] = emb[g * 50 + k];
  float t1[32];
  for (int j = 0; j < 32; j++) {
    float a = b1[j];
    for (int k = 0; k < 50; k++) a = fmaf(e[k], w1[k * 32 + j], a);
    t1[j] = a;
  }
  float t2[16];
  for (int j = 0; j < 16; j++) {
    float a = b2[j];
    for (int k = 0; k < 32; k++) a = fmaf(t1[k], w2[k * 16 + j], a);
    t2[j] = a;
  }
  float y = b3[0];
  for (int k = 0; k < 16; k++) y = fmaf(t2[k], w3[k], y);
  dout[g] = y;
}

// ---------------------------------------------------------------------------
extern "C" void kernel_launch(void* const* d_in, const int* in_sizes, int n_in,
                              void* d_out, int out_size, void* d_ws, size_t ws_size,
                              hipStream_t stream) {
  const float* x_in  = (const float*)d_in[0];
  const int*   eidx  = (const int*)d_in[1];   // int32 on device (JAX x64 off)
  const float* w_ih[3] = {(const float*)d_in[2], (const float*)d_in[6],  (const float*)d_in[10]};
  const float* w_hh[3] = {(const float*)d_in[3], (const float*)d_in[7],  (const float*)d_in[11]};
  const float* b_ih[3] = {(const float*)d_in[4], (const float*)d_in[8],  (const float*)d_in[12]};
  const float* b_hh[3] = {(const float*)d_in[5], (const float*)d_in[9],  (const float*)d_in[13]};
  const float* gw[4] = {(const float*)d_in[14], (const float*)d_in[16], (const float*)d_in[18], (const float*)d_in[20]};
  const float* gbv[4] = {(const float*)d_in[15], (const float*)d_in[17], (const float*)d_in[19], (const float*)d_in[21]};
  const float* fw1 = (const float*)d_in[22]; const float* fb1 = (const float*)d_in[23];
  const float* fw2 = (const float*)d_in[24]; const float* fb2 = (const float*)d_in[25];
  const float* fw3 = (const float*)d_in[26]; const float* fb3 = (const float*)d_in[27];
  const int* src = eidx;
  const int* dst = eidx + NEDGE;

  // workspace layout (floats)
  float* ws = (float*)d_ws;
  float* xp = ws;                                   // 2048*2560 = 5,242,880 f
  float* hs = ws + 5242880;                         // 2048*640  = 1,310,720 f
  unsigned int* cnt = (unsigned int*)(ws + 6553600);// 3*2048 u32
  unsigned int* deg = cnt + 6144;                   // 2048 u32
  float* dinv = (float*)(deg + 2048);               // 2048 f
  float* emb  = dinv + 2048;                        // 800 f
  // GCN buffers alias the (then-dead) xp region
  float* ga = xp;                // xw      (<= 2048*320)
  float* gb = xp + 655360;       // scatter (<= 2048*320)
  float* x0 = xp + 1310720;
  float* x1 = xp + 1966080;

  hipMemsetAsync(cnt, 0, 6144 * sizeof(unsigned int), stream);
  hipMemsetAsync(deg, 0, 2048 * sizeof(unsigned int), stream);

  const dim3 ggrid(GD / 64, NNODES / 64);
  // LSTM layer 0
  gemm_abt<<<ggrid, 256, 0, stream>>>(x_in, w_ih[0], b_ih[0], b_hh[0], xp, NNODES, GD, KIN);
  lstm_scan<<<SB, 256, 0, stream>>>(xp, w_hh[0], hs, cnt);
  // layer 1
  gemm_abt<<<ggrid, 256, 0, stream>>>(hs, w_ih[1], b_ih[1], b_hh[1], xp, NNODES, GD, HD);
  lstm_scan<<<SB, 256, 0, stream>>>(xp, w_hh[1], hs, cnt + 2048);
  // layer 2
  gemm_abt<<<ggrid, 256, 0, stream>>>(hs, w_ih[2], b_ih[2], b_hh[2], xp, NNODES, GD, HD);
  lstm_scan<<<SB, 256, 0, stream>>>(xp, w_hh[2], hs, cnt + 4096);

  // degree / normalization (once)
  deg_kernel<<<NEDGE / 256, 256, 0, stream>>>(dst, deg);
  dinv_kernel<<<NNODES / 256, 256, 0, stream>>>(deg, dinv);

  const int dims_in[4]  = {640, 320, 180, 90};
  const int dims_out[4] = {320, 180, 90, 50};
  const float* xin_l[4] = {hs, x0, x1, x0};
  float* xout_l[4]      = {x0, x1, x0, x1};
  for (int l = 0; l < 4; l++) {
    gcn_gemm<<<NNODES, 256, 0, stream>>>(xin_l[l], gw[l], ga, dims_in[l], dims_out[l]);
    hipMemsetAsync(gb, 0, (size_t)NNODES * dims_out[l] * sizeof(float), stream);
    gcn_scatter<<<NEDGE, 128, 0, stream>>>(ga, src, dst, dinv, gb, dims_out[l]);
    gcn_bn<<<dims_out[l], 256, 0, stream>>>(gb, ga, dinv, gbv[l], xout_l[l], dims_out[l]);
  }

  pool_kernel<<<NGRAPH, 64, 0, stream>>>(x1, emb, (float*)d_out);
  fc_head<<<1, 64, 0, stream>>>(emb, fw1, fb1, fw2, fb2, fw3, fb3, (float*)d_out);
}

// Round 2
// 14767.969 us; speedup vs baseline: 2.8993x; 2.8993x over previous
//
#include <hip/hip_runtime.h>
#include <stdint.h>

#define NNODES 2048
#define T_SEQ  2048
#define HD     640
#define GD     2560   // 4*HD
#define KIN    8500
#define NEDGE  65536
#define NGRAPH 16
#define SB     64     // blocks per layer
#define SDP    10     // h-dims per block
#define SENTU  0x7F7F7F7FU

// ---------------------------------------------------------------------------
// Generic C[M,N] = A[M,K] @ W[N,K]^T + b1[n] + b2[n]   (fp32, 64x64x16 tile)
// ---------------------------------------------------------------------------
__global__ __launch_bounds__(256) void gemm_abt(
    const float* __restrict__ A, const float* __restrict__ W,
    const float* __restrict__ b1, const float* __restrict__ b2,
    float* __restrict__ C, int M, int N, int K) {
  __shared__ float As[16][64];
  __shared__ float Ws[16][64];
  const int tid = threadIdx.x;
  const int bm = blockIdx.y * 64, bn = blockIdx.x * 64;
  const int lr = tid >> 2;
  const int lc4 = (tid & 3) << 2;
  const int ty = tid >> 4, tx = tid & 15;
  float acc[4][4] = {};
  const long lK = K;
  for (int k0 = 0; k0 < K; k0 += 16) {
    float a0=0.f,a1=0.f,a2=0.f,a3=0.f, w0=0.f,w1=0.f,w2=0.f,w3=0.f;
    const int ka = k0 + lc4;
    const float* Ap = A + (long)(bm + lr) * lK;
    const float* Wp = W + (long)(bn + lr) * lK;
    if (ka + 3 < K) {
      float4 av = *(const float4*)(Ap + ka);
      float4 wv = *(const float4*)(Wp + ka);
      a0=av.x; a1=av.y; a2=av.z; a3=av.w;
      w0=wv.x; w1=wv.y; w2=wv.z; w3=wv.w;
    } else {
      if (ka     < K) { a0 = Ap[ka];   w0 = Wp[ka];   }
      if (ka + 1 < K) { a1 = Ap[ka+1]; w1 = Wp[ka+1]; }
      if (ka + 2 < K) { a2 = Ap[ka+2]; w2 = Wp[ka+2]; }
    }
    __syncthreads();
    As[lc4+0][lr]=a0; As[lc4+1][lr]=a1; As[lc4+2][lr]=a2; As[lc4+3][lr]=a3;
    Ws[lc4+0][lr]=w0; Ws[lc4+1][lr]=w1; Ws[lc4+2][lr]=w2; Ws[lc4+3][lr]=w3;
    __syncthreads();
#pragma unroll
    for (int kk = 0; kk < 16; kk++) {
      float4 a4 = *(const float4*)&As[kk][ty<<2];
      float4 w4 = *(const float4*)&Ws[kk][tx<<2];
      float avv[4] = {a4.x,a4.y,a4.z,a4.w};
      float wvv[4] = {w4.x,w4.y,w4.z,w4.w};
#pragma unroll
      for (int i = 0; i < 4; i++)
#pragma unroll
        for (int j = 0; j < 4; j++)
          acc[i][j] = fmaf(avv[i], wvv[j], acc[i][j]);
    }
  }
#pragma unroll
  for (int i = 0; i < 4; i++) {
    const int m = bm + (ty<<2) + i;
#pragma unroll
    for (int j = 0; j < 4; j++) {
      const int n = bn + (tx<<2) + j;
      C[(long)m * N + n] = acc[i][j] + b1[n] + b2[n];
    }
  }
}

// ---------------------------------------------------------------------------
// Fused 3-layer pipelined LSTM scan.
// grid = 192: layer = blockIdx.x/64, b = blockIdx.x%64 owns h-dims [b*10,b*10+10).
// Sentinel-valued data IS the flag: hs* pre-filled 0x7F7F7F7F; producers do
// relaxed agent-scope atomic stores of h; consumers poll the words directly.
// ---------------------------------------------------------------------------
__device__ __forceinline__ unsigned f2bf(float x) {
  unsigned u = __float_as_uint(x);
  return (u + 0x7fffu + ((u >> 16) & 1u)) >> 16;
}

__device__ __forceinline__ float bfdot(unsigned u, float2 h, float acc) {
  acc = fmaf(h.x, __uint_as_float(u << 16), acc);
  acc = fmaf(h.y, __uint_as_float(u & 0xffff0000u), acc);
  return acc;
}

// poll 640 floats (as 5 u64 per lane) from src until non-sentinel; write to LDS dst
__device__ __forceinline__ void poll_row(const float* __restrict__ src,
                                         float* __restrict__ dst, int lane) {
  const unsigned long long* p = (const unsigned long long*)src;
  unsigned pend = 0x1Fu;
  uint2 v[5];
  long spins = 0;
  while (pend) {
#pragma unroll
    for (int m = 0; m < 5; m++) {
      if (pend & (1u << m)) {
        unsigned long long u = __hip_atomic_load(p + lane + 64 * m,
            __ATOMIC_RELAXED, __HIP_MEMORY_SCOPE_AGENT);
        unsigned lo = (unsigned)u, hi = (unsigned)(u >> 32);
        if (lo != SENTU && hi != SENTU) { v[m].x = lo; v[m].y = hi; pend &= ~(1u << m); }
      }
    }
    if (pend) {
      if (++spins > 20000000L) break;  // safety: wrong > hung
      __builtin_amdgcn_s_sleep(2);
    }
  }
  uint2* d2 = (uint2*)dst;
#pragma unroll
  for (int m = 0; m < 5; m++) d2[lane + 64 * m] = v[m];
}

__global__ __launch_bounds__(256, 1) void fused_scan(
    const float* __restrict__ xp,     // [T,2560] layer-0 input proj (+biases)
    const float* __restrict__ whh0,
    const float* __restrict__ wih1, const float* __restrict__ whh1,
    const float* __restrict__ bih1, const float* __restrict__ bhh1,
    const float* __restrict__ wih2, const float* __restrict__ whh2,
    const float* __restrict__ bih2, const float* __restrict__ bhh2,
    float* __restrict__ hs0, float* __restrict__ hs1, float* __restrict__ hs2) {
  // mat 0 = W_ih (layers 1,2 only), mat 1 = W_hh. Packed bf16 pairs:
  // u32 #m of (row r, lane) covers k = 2*(lane+64m), 2*(lane+64m)+1.
  __shared__ uint4    w4[2][40 * 64];
  __shared__ unsigned w1s[2][40 * 64];
  __shared__ __align__(16) float hbuf[640];
  __shared__ __align__(16) float xbuf[640];
  __shared__ float gdot[40];
  __shared__ float gext[40];   // layer0: xp scalars per step; layers 1,2: biases
  const int tid = threadIdx.x;
  const int l = blockIdx.x / SB, b = blockIdx.x % SB;
  const int lane = tid & 63, wv = tid >> 6;

  const float* Wih = (l == 1) ? wih1 : wih2;
  const float* Whh = (l == 0) ? whh0 : ((l == 1) ? whh1 : whh2);
  const float* hin = (l == 1) ? hs0 : hs1;         // unused for l==0
  float* hout = (l == 0) ? hs0 : ((l == 1) ? hs1 : hs2);

  // stage weight slices -> LDS bf16
  for (int idx = tid; idx < 40 * 64; idx += 256) {
    const int r = idx >> 6, ln = idx & 63;
    const int g = r / SDP, d = r - g * SDP;
    const long grow = (long)(g * HD + b * SDP + d) * HD;
    unsigned um[5];
    const float* wr = Whh + grow;
#pragma unroll
    for (int m = 0; m < 5; m++) {
      float2 wp = *(const float2*)(wr + 2 * (ln + 64 * m));
      um[m] = f2bf(wp.x) | (f2bf(wp.y) << 16);
    }
    w4[1][idx] = make_uint4(um[0], um[1], um[2], um[3]);
    w1s[1][idx] = um[4];
    if (l > 0) {
      const float* wr2 = Wih + grow;
#pragma unroll
      for (int m = 0; m < 5; m++) {
        float2 wp = *(const float2*)(wr2 + 2 * (ln + 64 * m));
        um[m] = f2bf(wp.x) | (f2bf(wp.y) << 16);
      }
      w4[0][idx] = make_uint4(um[0], um[1], um[2], um[3]);
      w1s[0][idx] = um[4];
    }
  }
  if (l > 0 && tid < 40) {
    const int g = tid / SDP, d = tid - g * SDP;
    const float* bi = (l == 1) ? bih1 : bih2;
    const float* bh = (l == 1) ? bhh1 : bhh2;
    gext[tid] = bi[g * HD + b * SDP + d] + bh[g * HD + b * SDP + d];
  }
  __syncthreads();

  float creg = 0.f;  // cell state for tid < SDP
  for (int t = 0; t < T_SEQ; t++) {
    if (l == 0 && wv == 2 && lane < 40) {   // idle wave fetches xp scalars
      const int g = lane / SDP, d = lane - g * SDP;
      gext[lane] = xp[(long)t * GD + g * HD + b * SDP + d];
    }
    if (wv == 0) {
      if (t > 0) {
        poll_row(hout + (long)(t - 1) * HD, hbuf, lane);
      } else {
        uint2 z; z.x = 0u; z.y = 0u;
        uint2* d2 = (uint2*)hbuf;
#pragma unroll
        for (int m = 0; m < 5; m++) d2[lane + 64 * m] = z;
      }
    }
    if (l > 0 && wv == 1) poll_row(hin + (long)t * HD, xbuf, lane);
    __syncthreads();

    // dot products: wave wv = gate, 10 rows each
    float2 hv[5], xv[5];
#pragma unroll
    for (int m = 0; m < 5; m++) hv[m] = ((const float2*)hbuf)[lane + 64 * m];
    if (l > 0) {
#pragma unroll
      for (int m = 0; m < 5; m++) xv[m] = ((const float2*)xbuf)[lane + 64 * m];
    }
#pragma unroll
    for (int d = 0; d < SDP; d++) {
      const int r = wv * SDP + d;
      const uint4 a = w4[1][r * 64 + lane];
      const unsigned a4 = w1s[1][r * 64 + lane];
      float p = 0.f;
      p = bfdot(a.x, hv[0], p); p = bfdot(a.y, hv[1], p);
      p = bfdot(a.z, hv[2], p); p = bfdot(a.w, hv[3], p);
      p = bfdot(a4,  hv[4], p);
      if (l > 0) {
        const uint4 c = w4[0][r * 64 + lane];
        const unsigned c4 = w1s[0][r * 64 + lane];
        p = bfdot(c.x, xv[0], p); p = bfdot(c.y, xv[1], p);
        p = bfdot(c.z, xv[2], p); p = bfdot(c.w, xv[3], p);
        p = bfdot(c4,  xv[4], p);
      }
#pragma unroll
      for (int off = 32; off; off >>= 1) p += __shfl_down(p, off, 64);
      if (lane == 0) gdot[r] = p;
    }
    __syncthreads();

    if (tid < SDP) {
      const float gi = gext[tid]           + gdot[tid];
      const float gf = gext[SDP + tid]     + gdot[SDP + tid];
      const float gg = gext[2 * SDP + tid] + gdot[2 * SDP + tid];
      const float go = gext[3 * SDP + tid] + gdot[3 * SDP + tid];
      const float si = 1.f / (1.f + expf(-gi));
      const float sf = 1.f / (1.f + expf(-gf));
      const float so = 1.f / (1.f + expf(-go));
      creg = sf * creg + si * tanhf(gg);
      const float h = so * tanhf(creg);
      __hip_atomic_store((unsigned*)(hout + (long)t * HD + b * SDP + tid),
                         __float_as_uint(h), __ATOMIC_RELAXED,
                         __HIP_MEMORY_SCOPE_AGENT);
    }
    __syncthreads();  // protect hbuf/xbuf/gext/gdot before next iteration
  }
}

// ---------------------------------------------------------------------------
// GCN pieces
// ---------------------------------------------------------------------------
__global__ __launch_bounds__(256) void gcn_gemm(
    const float* __restrict__ X, const float* __restrict__ W,
    float* __restrict__ Y, int di, int dout) {
  __shared__ float xr[640];
  const int n = blockIdx.x;
  for (int k = threadIdx.x; k < di; k += 256) xr[k] = X[(long)n * di + k];
  __syncthreads();
  for (int c = threadIdx.x; c < dout; c += 256) {
    float acc = 0.f;
    for (int k = 0; k < di; k++) acc = fmaf(xr[k], W[(long)k * dout + c], acc);
    Y[(long)n * dout + c] = acc;
  }
}

__global__ void deg_kernel(const int* __restrict__ dst, unsigned int* __restrict__ deg) {
  const int e = blockIdx.x * 256 + threadIdx.x;
  if (e < NEDGE) atomicAdd(&deg[dst[e]], 1u);
}

__global__ void dinv_kernel(const unsigned int* __restrict__ deg, float* __restrict__ dinv) {
  const int n = blockIdx.x * 256 + threadIdx.x;
  if (n < NNODES) dinv[n] = 1.f / sqrtf((float)(deg[n] + 1u));
}

__global__ __launch_bounds__(128) void gcn_scatter(
    const float* __restrict__ XW, const int* __restrict__ src,
    const int* __restrict__ dst, const float* __restrict__ dinv,
    float* __restrict__ out, int dout) {
  const int e = blockIdx.x;
  const int s = src[e], d = dst[e];
  const float nrm = dinv[s] * dinv[d];
  for (int c = threadIdx.x; c < dout; c += 128)
    atomicAdd(&out[(long)d * dout + c], XW[(long)s * dout + c] * nrm);
}

__global__ __launch_bounds__(256) void gcn_bn(
    const float* __restrict__ scat, const float* __restrict__ xw,
    const float* __restrict__ dinv, const float* __restrict__ bias,
    float* __restrict__ out, int dout) {
  const int c = blockIdx.x;
  const float bc = bias[c];
  float s = 0.f, s2 = 0.f;
  for (int n = threadIdx.x; n < NNODES; n += 256) {
    float v = scat[(long)n * dout + c] + xw[(long)n * dout + c] * dinv[n] * dinv[n] + bc;
    v = v >= 0.f ? v : 0.01f * v;
    s += v; s2 += v * v;
  }
  __shared__ float rs[4], rs2[4];
#pragma unroll
  for (int off = 32; off; off >>= 1) { s += __shfl_down(s, off, 64); s2 += __shfl_down(s2, off, 64); }
  const int w = threadIdx.x >> 6;
  if ((threadIdx.x & 63) == 0) { rs[w] = s; rs2[w] = s2; }
  __syncthreads();
  const float ts  = rs[0] + rs[1] + rs[2] + rs[3];
  const float ts2 = rs2[0] + rs2[1] + rs2[2] + rs2[3];
  const float mu = ts * (1.f / (float)NNODES);
  const float var = ts2 * (1.f / (float)NNODES) - mu * mu;
  const float rstd = 1.f / sqrtf(var + 1e-5f);
  for (int n = threadIdx.x; n < NNODES; n += 256) {
    float v = scat[(long)n * dout + c] + xw[(long)n * dout + c] * dinv[n] * dinv[n] + bc;
    v = v >= 0.f ? v : 0.01f * v;
    out[(long)n * dout + c] = (v - mu) * rstd;
  }
}

__global__ __launch_bounds__(64) void pool_kernel(
    const float* __restrict__ x, float* __restrict__ emb, float* __restrict__ dout) {
  const int g = blockIdx.x, c = threadIdx.x;
  if (c >= 50) return;
  float s = 0.f;
  for (int r = 0; r < 128; r++) s += x[(long)(g * 128 + r) * 50 + c];
  emb[g * 50 + c] = s;
  dout[16 + g * 50 + c] = s;
}

__global__ __launch_bounds__(64) void fc_head(
    const float* __restrict__ emb,
    const float* __restrict__ w1, const float* __restrict__ b1,
    const float* __restrict__ w2, const float* __restrict__ b2,
    const float* __restrict__ w3, const float* __restrict__ b3,
    float* __restrict__ dout) {
  const int g = threadIdx.x;
  if (g >= NGRAPH) return;
  float e[50];
#pragma unroll
  for (int k = 0; k < 50; k++) e[k] = emb[g * 50 + k];
  float t1[32];
  for (int j = 0; j < 32; j++) {
    float a = b1[j];
    for (int k = 0; k < 50; k++) a = fmaf(e[k], w1[k * 32 + j], a);
    t1[j] = a;
  }
  float t2[16];
  for (int j = 0; j < 16; j++) {
    float a = b2[j];
    for (int k = 0; k < 32; k++) a = fmaf(t1[k], w2[k * 16 + j], a);
    t2[j] = a;
  }
  float y = b3[0];
  for (int k = 0; k < 16; k++) y = fmaf(t2[k], w3[k], y);
  dout[g] = y;
}

// ---------------------------------------------------------------------------
extern "C" void kernel_launch(void* const* d_in, const int* in_sizes, int n_in,
                              void* d_out, int out_size, void* d_ws, size_t ws_size,
                              hipStream_t stream) {
  const float* x_in  = (const float*)d_in[0];
  const int*   eidx  = (const int*)d_in[1];
  const float* w_ih[3] = {(const float*)d_in[2], (const float*)d_in[6],  (const float*)d_in[10]};
  const float* w_hh[3] = {(const float*)d_in[3], (const float*)d_in[7],  (const float*)d_in[11]};
  const float* b_ih[3] = {(const float*)d_in[4], (const float*)d_in[8],  (const float*)d_in[12]};
  const float* b_hh[3] = {(const float*)d_in[5], (const float*)d_in[9],  (const float*)d_in[13]};
  const float* gw[4] = {(const float*)d_in[14], (const float*)d_in[16], (const float*)d_in[18], (const float*)d_in[20]};
  const float* gbv[4] = {(const float*)d_in[15], (const float*)d_in[17], (const float*)d_in[19], (const float*)d_in[21]};
  const float* fw1 = (const float*)d_in[22]; const float* fb1 = (const float*)d_in[23];
  const float* fw2 = (const float*)d_in[24]; const float* fb2 = (const float*)d_in[25];
  const float* fw3 = (const float*)d_in[26]; const float* fb3 = (const float*)d_in[27];
  const int* src = eidx;
  const int* dst = eidx + NEDGE;

  // workspace layout (floats)
  float* ws  = (float*)d_ws;
  float* xp  = ws;                      // 5,242,880 f
  float* hs0 = ws + 5242880;            // 1,310,720 f
  float* hs1 = hs0 + 1310720;
  float* hs2 = hs1 + 1310720;
  unsigned int* deg = (unsigned int*)(hs2 + 1310720);
  float* dinv = (float*)(deg + 2048);
  float* emb  = dinv + 2048;
  // GCN buffers alias the (then-dead) xp region
  float* ga = xp;
  float* gb = xp + 655360;
  float* x0 = xp + 1310720;
  float* x1 = xp + 1966080;

  // sentinel-fill the three h buffers (contiguous), zero deg
  hipMemsetAsync(hs0, 0x7F, (size_t)3 * 1310720 * sizeof(float), stream);
  hipMemsetAsync(deg, 0, 2048 * sizeof(unsigned int), stream);

  // layer-0 input projection (K=8500) + both biases
  gemm_abt<<<dim3(GD / 64, NNODES / 64), 256, 0, stream>>>(
      x_in, w_ih[0], b_ih[0], b_hh[0], xp, NNODES, GD, KIN);

  deg_kernel<<<NEDGE / 256, 256, 0, stream>>>(dst, deg);
  dinv_kernel<<<NNODES / 256, 256, 0, stream>>>(deg, dinv);

  // pipelined 3-layer scan
  fused_scan<<<3 * SB, 256, 0, stream>>>(
      xp, w_hh[0], w_ih[1], w_hh[1], b_ih[1], b_hh[1],
      w_ih[2], w_hh[2], b_ih[2], b_hh[2], hs0, hs1, hs2);

  const int dims_in[4]  = {640, 320, 180, 90};
  const int dims_out[4] = {320, 180, 90, 50};
  const float* xin_l[4] = {hs2, x0, x1, x0};
  float* xout_l[4]      = {x0, x1, x0, x1};
  for (int l = 0; l < 4; l++) {
    gcn_gemm<<<NNODES, 256, 0, stream>>>(xin_l[l], gw[l], ga, dims_in[l], dims_out[l]);
    hipMemsetAsync(gb, 0, (size_t)NNODES * dims_out[l] * sizeof(float), stream);
    gcn_scatter<<<NEDGE, 128, 0, stream>>>(ga, src, dst, dinv, gb, dims_out[l]);
    gcn_bn<<<dims_out[l], 256, 0, stream>>>(gb, ga, dinv, gbv[l], xout_l[l], dims_out[l]);
  }

  pool_kernel<<<NGRAPH, 64, 0, stream>>>(x1, emb, (float*)d_out);
  fc_head<<<1, 64, 0, stream>>>(emb, fw1, fb1, fw2, fb2, fw3, fb3, (float*)d_out);
}

// Round 3
// 14149.574 us; speedup vs baseline: 3.0261x; 1.0437x over previous
//
#include <hip/hip_runtime.h>
#include <stdint.h>

#define NNODES 2048
#define T_SEQ  2048
#define HD     640
#define GD     2560   // 4*HD
#define KIN    8500
#define NEDGE  65536
#define NGRAPH 16
#define SB     64     // blocks per layer
#define SDP    10     // h-dims per block
#define SENTU  0x7F7F7F7FU
#define GATEW  1      // wave that computes gates / produces h

// ---------------------------------------------------------------------------
// Generic C[M,N] = A[M,K] @ W[N,K]^T + b1[n] + b2[n]   (fp32, 64x64x16 tile)
// ---------------------------------------------------------------------------
__global__ __launch_bounds__(256) void gemm_abt(
    const float* __restrict__ A, const float* __restrict__ W,
    const float* __restrict__ b1, const float* __restrict__ b2,
    float* __restrict__ C, int M, int N, int K) {
  __shared__ float As[16][64];
  __shared__ float Ws[16][64];
  const int tid = threadIdx.x;
  const int bm = blockIdx.y * 64, bn = blockIdx.x * 64;
  const int lr = tid >> 2;
  const int lc4 = (tid & 3) << 2;
  const int ty = tid >> 4, tx = tid & 15;
  float acc[4][4] = {};
  const long lK = K;
  for (int k0 = 0; k0 < K; k0 += 16) {
    float a0=0.f,a1=0.f,a2=0.f,a3=0.f, w0=0.f,w1=0.f,w2=0.f,w3=0.f;
    const int ka = k0 + lc4;
    const float* Ap = A + (long)(bm + lr) * lK;
    const float* Wp = W + (long)(bn + lr) * lK;
    if (ka + 3 < K) {
      float4 av = *(const float4*)(Ap + ka);
      float4 wv = *(const float4*)(Wp + ka);
      a0=av.x; a1=av.y; a2=av.z; a3=av.w;
      w0=wv.x; w1=wv.y; w2=wv.z; w3=wv.w;
    } else {
      if (ka     < K) { a0 = Ap[ka];   w0 = Wp[ka];   }
      if (ka + 1 < K) { a1 = Ap[ka+1]; w1 = Wp[ka+1]; }
      if (ka + 2 < K) { a2 = Ap[ka+2]; w2 = Wp[ka+2]; }
    }
    __syncthreads();
    As[lc4+0][lr]=a0; As[lc4+1][lr]=a1; As[lc4+2][lr]=a2; As[lc4+3][lr]=a3;
    Ws[lc4+0][lr]=w0; Ws[lc4+1][lr]=w1; Ws[lc4+2][lr]=w2; Ws[lc4+3][lr]=w3;
    __syncthreads();
#pragma unroll
    for (int kk = 0; kk < 16; kk++) {
      float4 a4 = *(const float4*)&As[kk][ty<<2];
      float4 w4 = *(const float4*)&Ws[kk][tx<<2];
      float avv[4] = {a4.x,a4.y,a4.z,a4.w};
      float wvv[4] = {w4.x,w4.y,w4.z,w4.w};
#pragma unroll
      for (int i = 0; i < 4; i++)
#pragma unroll
        for (int j = 0; j < 4; j++)
          acc[i][j] = fmaf(avv[i], wvv[j], acc[i][j]);
    }
  }
#pragma unroll
  for (int i = 0; i < 4; i++) {
    const int m = bm + (ty<<2) + i;
#pragma unroll
    for (int j = 0; j < 4; j++) {
      const int n = bn + (tx<<2) + j;
      C[(long)m * N + n] = acc[i][j] + b1[n] + b2[n];
    }
  }
}

// ---------------------------------------------------------------------------
// Fused 3-layer pipelined LSTM scan (2 barriers/step, multi-wave polling).
// ---------------------------------------------------------------------------
__device__ __forceinline__ unsigned f2bf(float x) {
  unsigned u = __float_as_uint(x);
  return (u + 0x7fffu + ((u >> 16) & 1u)) >> 16;
}

__device__ __forceinline__ float bfdot(unsigned u, float2 h, float acc) {
  acc = fmaf(h.x, __uint_as_float(u << 16), acc);
  acc = fmaf(h.y, __uint_as_float(u & 0xffff0000u), acc);
  return acc;
}

// Poll chunks c = pid + m*np (m=0,1,2; c<320) of a 640-float row; skip
// [skip_lo,skip_hi); drain each detected 8B chunk to LDS immediately.
__device__ __forceinline__ void poll_part(
    const float* __restrict__ src, float* __restrict__ dst,
    int pid, int np, int skip_lo, int skip_hi, bool zero) {
  uint2* d2 = (uint2*)dst;
  if (zero) {
    for (int c = pid; c < 320; c += np) d2[c] = make_uint2(0u, 0u);
    return;
  }
  const unsigned long long* p = (const unsigned long long*)src;
  const int c0 = pid, c1 = pid + np, c2 = pid + 2 * np;
  unsigned pend = 0;
  if (c0 < 320 && !(c0 >= skip_lo && c0 < skip_hi)) pend |= 1u;
  if (c1 < 320 && !(c1 >= skip_lo && c1 < skip_hi)) pend |= 2u;
  if (c2 < 320 && !(c2 >= skip_lo && c2 < skip_hi)) pend |= 4u;
  long spins = 0;
  while (pend) {
    unsigned long long u0 = 0, u1 = 0, u2 = 0;
    if (pend & 1u) u0 = __hip_atomic_load(p + c0, __ATOMIC_RELAXED, __HIP_MEMORY_SCOPE_AGENT);
    if (pend & 2u) u1 = __hip_atomic_load(p + c1, __ATOMIC_RELAXED, __HIP_MEMORY_SCOPE_AGENT);
    if (pend & 4u) u2 = __hip_atomic_load(p + c2, __ATOMIC_RELAXED, __HIP_MEMORY_SCOPE_AGENT);
    if ((pend & 1u) && (unsigned)u0 != SENTU && (unsigned)(u0 >> 32) != SENTU) {
      d2[c0] = make_uint2((unsigned)u0, (unsigned)(u0 >> 32)); pend &= ~1u;
    }
    if ((pend & 2u) && (unsigned)u1 != SENTU && (unsigned)(u1 >> 32) != SENTU) {
      d2[c1] = make_uint2((unsigned)u1, (unsigned)(u1 >> 32)); pend &= ~2u;
    }
    if ((pend & 4u) && (unsigned)u2 != SENTU && (unsigned)(u2 >> 32) != SENTU) {
      d2[c2] = make_uint2((unsigned)u2, (unsigned)(u2 >> 32)); pend &= ~4u;
    }
    if (pend) {
      if (++spins > 20000000L) break;  // safety: wrong > hung
      __builtin_amdgcn_s_sleep(1);
    }
  }
}

__global__ __launch_bounds__(256, 1) void fused_scan(
    const float* __restrict__ xp,
    const float* __restrict__ whh0,
    const float* __restrict__ wih1, const float* __restrict__ whh1,
    const float* __restrict__ bih1, const float* __restrict__ bhh1,
    const float* __restrict__ wih2, const float* __restrict__ whh2,
    const float* __restrict__ bih2, const float* __restrict__ bhh2,
    float* __restrict__ hs0, float* __restrict__ hs1, float* __restrict__ hs2) {
  __shared__ uint4    w4[2][40 * 64];
  __shared__ unsigned w1s[2][40 * 64];
  __shared__ __align__(16) float hbuf[640];
  __shared__ __align__(16) float xbuf[640];
  __shared__ float gdot[40];
  __shared__ float gext[2][40];   // parity-buffered per-step externals
  const int tid = threadIdx.x;
  const int l = blockIdx.x / SB, b = blockIdx.x % SB;
  const int lane = tid & 63, wv = tid >> 6;

  const float* Wih = (l == 1) ? wih1 : wih2;
  const float* Whh = (l == 0) ? whh0 : ((l == 1) ? whh1 : whh2);
  const float* hin = (l == 1) ? hs0 : hs1;
  float* hout = (l == 0) ? hs0 : ((l == 1) ? hs1 : hs2);

  // stage weight slices -> LDS bf16
  for (int idx = tid; idx < 40 * 64; idx += 256) {
    const int r = idx >> 6, ln = idx & 63;
    const int g = r / SDP, d = r - g * SDP;
    const long grow = (long)(g * HD + b * SDP + d) * HD;
    unsigned um[5];
    const float* wr = Whh + grow;
#pragma unroll
    for (int m = 0; m < 5; m++) {
      float2 wp = *(const float2*)(wr + 2 * (ln + 64 * m));
      um[m] = f2bf(wp.x) | (f2bf(wp.y) << 16);
    }
    w4[1][idx] = make_uint4(um[0], um[1], um[2], um[3]);
    w1s[1][idx] = um[4];
    if (l > 0) {
      const float* wr2 = Wih + grow;
#pragma unroll
      for (int m = 0; m < 5; m++) {
        float2 wp = *(const float2*)(wr2 + 2 * (ln + 64 * m));
        um[m] = f2bf(wp.x) | (f2bf(wp.y) << 16);
      }
      w4[0][idx] = make_uint4(um[0], um[1], um[2], um[3]);
      w1s[0][idx] = um[4];
    }
  }
  if (l > 0 && tid < 40) {
    const int g = tid / SDP, d = tid - g * SDP;
    const float* bi = (l == 1) ? bih1 : bih2;
    const float* bh = (l == 1) ? bhh1 : bhh2;
    const float bb = bi[g * HD + b * SDP + d] + bh[g * HD + b * SDP + d];
    gext[0][tid] = bb; gext[1][tid] = bb;
  }

  // xp prefetch (l==0, wave 3, lanes<40): register holds xp value for step t
  float xnext = 0.f;
  int gxi = 0;
  if (l == 0 && wv == 3 && lane < 40) {
    gxi = (lane / SDP) * HD + b * SDP + (lane - (lane / SDP) * SDP);
    xnext = xp[gxi];   // t = 0
  }
  __syncthreads();

  const int own_lo = b * (SDP / 2);       // 5 u64 chunks per block (SDP=10)
  const int own_hi = own_lo + SDP / 2;

  float creg = 0.f;
  for (int t = 0; t < T_SEQ; t++) {
    // ---- top: fill hbuf/xbuf/gext (no global latency on l==0 gext path)
    if (l == 0) {
      if (wv == 3 && lane < 40) {
        gext[t & 1][lane] = xnext;
        if (t + 1 < T_SEQ) xnext = xp[(long)(t + 1) * GD + gxi];  // prefetch t+1
      }
      if (wv != GATEW) {  // waves 0,2,3 poll hbuf (np=192)
        const int pid = (wv == 0) ? lane : ((wv == 2) ? 64 + lane : 128 + lane);
        if (t == 0) poll_part(nullptr, hbuf, pid, 192, own_lo, own_hi, true);
        else poll_part(hout + (long)(t - 1) * HD, hbuf, pid, 192, own_lo, own_hi, false);
      }
    } else {
      if (wv == 0 || wv == 2) {  // hbuf: np=128
        const int pid = (wv == 0) ? lane : 64 + lane;
        if (t == 0) poll_part(nullptr, hbuf, pid, 128, own_lo, own_hi, true);
        else poll_part(hout + (long)(t - 1) * HD, hbuf, pid, 128, own_lo, own_hi, false);
      } else {                   // xbuf: waves 3,1 (wave 1 joins after gates)
        const int pid = (wv == 3) ? lane : 64 + lane;
        poll_part(hin + (long)t * HD, xbuf, pid, 128, -1, -1, false);
      }
    }
    __syncthreads();   // A: hbuf/xbuf/gext ready

    // ---- dots: wave wv = gate, 10 rows each
    float2 hv[5], xv[5];
#pragma unroll
    for (int m = 0; m < 5; m++) hv[m] = ((const float2*)hbuf)[lane + 64 * m];
    if (l > 0) {
#pragma unroll
      for (int m = 0; m < 5; m++) xv[m] = ((const float2*)xbuf)[lane + 64 * m];
    }
#pragma unroll
    for (int d = 0; d < SDP; d++) {
      const int r = wv * SDP + d;
      const uint4 a = w4[1][r * 64 + lane];
      const unsigned a4 = w1s[1][r * 64 + lane];
      float p = 0.f;
      p = bfdot(a.x, hv[0], p); p = bfdot(a.y, hv[1], p);
      p = bfdot(a.z, hv[2], p); p = bfdot(a.w, hv[3], p);
      p = bfdot(a4,  hv[4], p);
      if (l > 0) {
        const uint4 c = w4[0][r * 64 + lane];
        const unsigned c4 = w1s[0][r * 64 + lane];
        p = bfdot(c.x, xv[0], p); p = bfdot(c.y, xv[1], p);
        p = bfdot(c.z, xv[2], p); p = bfdot(c.w, xv[3], p);
        p = bfdot(c4,  xv[4], p);
      }
#pragma unroll
      for (int off = 32; off; off >>= 1) p += __shfl_down(p, off, 64);
      if (lane == 0) gdot[r] = p;
    }
    __syncthreads();   // B: gdot ready; hbuf/xbuf consumed

    // ---- gates (wave GATEW, lanes<10); then that wave loops to poll next row
    if (wv == GATEW && lane < SDP) {
      const float* ge = gext[t & 1];
      const float gi = ge[lane]           + gdot[lane];
      const float gf = ge[SDP + lane]     + gdot[SDP + lane];
      const float gg = ge[2 * SDP + lane] + gdot[2 * SDP + lane];
      const float go = ge[3 * SDP + lane] + gdot[3 * SDP + lane];
      const float si = 1.f / (1.f + expf(-gi));
      const float sf = 1.f / (1.f + expf(-gf));
      const float so = 1.f / (1.f + expf(-go));
      creg = sf * creg + si * tanhf(gg);
      const float h = so * tanhf(creg);
      __hip_atomic_store((unsigned*)(hout + (long)t * HD + b * SDP + lane),
                         __float_as_uint(h), __ATOMIC_RELAXED,
                         __HIP_MEMORY_SCOPE_AGENT);
      hbuf[b * SDP + lane] = h;   // own slice for step t+1 (pollers skip it)
    }
  }
}

// ---------------------------------------------------------------------------
// GCN pieces
// ---------------------------------------------------------------------------
__global__ __launch_bounds__(256) void gcn_gemm(
    const float* __restrict__ X, const float* __restrict__ W,
    float* __restrict__ Y, int di, int dout) {
  __shared__ float xr[640];
  const int n = blockIdx.x;
  for (int k = threadIdx.x; k < di; k += 256) xr[k] = X[(long)n * di + k];
  __syncthreads();
  for (int c = threadIdx.x; c < dout; c += 256) {
    float acc = 0.f;
    for (int k = 0; k < di; k++) acc = fmaf(xr[k], W[(long)k * dout + c], acc);
    Y[(long)n * dout + c] = acc;
  }
}

__global__ void deg_kernel(const int* __restrict__ dst, unsigned int* __restrict__ deg) {
  const int e = blockIdx.x * 256 + threadIdx.x;
  if (e < NEDGE) atomicAdd(&deg[dst[e]], 1u);
}

__global__ void dinv_kernel(const unsigned int* __restrict__ deg, float* __restrict__ dinv) {
  const int n = blockIdx.x * 256 + threadIdx.x;
  if (n < NNODES) dinv[n] = 1.f / sqrtf((float)(deg[n] + 1u));
}

__global__ __launch_bounds__(128) void gcn_scatter(
    const float* __restrict__ XW, const int* __restrict__ src,
    const int* __restrict__ dst, const float* __restrict__ dinv,
    float* __restrict__ out, int dout) {
  const int e = blockIdx.x;
  const int s = src[e], d = dst[e];
  const float nrm = dinv[s] * dinv[d];
  for (int c = threadIdx.x; c < dout; c += 128)
    atomicAdd(&out[(long)d * dout + c], XW[(long)s * dout + c] * nrm);
}

__global__ __launch_bounds__(256) void gcn_bn(
    const float* __restrict__ scat, const float* __restrict__ xw,
    const float* __restrict__ dinv, const float* __restrict__ bias,
    float* __restrict__ out, int dout) {
  const int c = blockIdx.x;
  const float bc = bias[c];
  float s = 0.f, s2 = 0.f;
  for (int n = threadIdx.x; n < NNODES; n += 256) {
    float v = scat[(long)n * dout + c] + xw[(long)n * dout + c] * dinv[n] * dinv[n] + bc;
    v = v >= 0.f ? v : 0.01f * v;
    s += v; s2 += v * v;
  }
  __shared__ float rs[4], rs2[4];
#pragma unroll
  for (int off = 32; off; off >>= 1) { s += __shfl_down(s, off, 64); s2 += __shfl_down(s2, off, 64); }
  const int w = threadIdx.x >> 6;
  if ((threadIdx.x & 63) == 0) { rs[w] = s; rs2[w] = s2; }
  __syncthreads();
  const float ts  = rs[0] + rs[1] + rs[2] + rs[3];
  const float ts2 = rs2[0] + rs2[1] + rs2[2] + rs2[3];
  const float mu = ts * (1.f / (float)NNODES);
  const float var = ts2 * (1.f / (float)NNODES) - mu * mu;
  const float rstd = 1.f / sqrtf(var + 1e-5f);
  for (int n = threadIdx.x; n < NNODES; n += 256) {
    float v = scat[(long)n * dout + c] + xw[(long)n * dout + c] * dinv[n] * dinv[n] + bc;
    v = v >= 0.f ? v : 0.01f * v;
    out[(long)n * dout + c] = (v - mu) * rstd;
  }
}

__global__ __launch_bounds__(64) void pool_kernel(
    const float* __restrict__ x, float* __restrict__ emb, float* __restrict__ dout) {
  const int g = blockIdx.x, c = threadIdx.x;
  if (c >= 50) return;
  float s = 0.f;
  for (int r = 0; r < 128; r++) s += x[(long)(g * 128 + r) * 50 + c];
  emb[g * 50 + c] = s;
  dout[16 + g * 50 + c] = s;
}

__global__ __launch_bounds__(64) void fc_head(
    const float* __restrict__ emb,
    const float* __restrict__ w1, const float* __restrict__ b1,
    const float* __restrict__ w2, const float* __restrict__ b2,
    const float* __restrict__ w3, const float* __restrict__ b3,
    float* __restrict__ dout) {
  const int g = threadIdx.x;
  if (g >= NGRAPH) return;
  float e[50];
#pragma unroll
  for (int k = 0; k < 50; k++) e[k] = emb[g * 50 + k];
  float t1[32];
  for (int j = 0; j < 32; j++) {
    float a = b1[j];
    for (int k = 0; k < 50; k++) a = fmaf(e[k], w1[k * 32 + j], a);
    t1[j] = a;
  }
  float t2[16];
  for (int j = 0; j < 16; j++) {
    float a = b2[j];
    for (int k = 0; k < 32; k++) a = fmaf(t1[k], w2[k * 16 + j], a);
    t2[j] = a;
  }
  float y = b3[0];
  for (int k = 0; k < 16; k++) y = fmaf(t2[k], w3[k], y);
  dout[g] = y;
}

// ---------------------------------------------------------------------------
extern "C" void kernel_launch(void* const* d_in, const int* in_sizes, int n_in,
                              void* d_out, int out_size, void* d_ws, size_t ws_size,
                              hipStream_t stream) {
  const float* x_in  = (const float*)d_in[0];
  const int*   eidx  = (const int*)d_in[1];
  const float* w_ih[3] = {(const float*)d_in[2], (const float*)d_in[6],  (const float*)d_in[10]};
  const float* w_hh[3] = {(const float*)d_in[3], (const float*)d_in[7],  (const float*)d_in[11]};
  const float* b_ih[3] = {(const float*)d_in[4], (const float*)d_in[8],  (const float*)d_in[12]};
  const float* b_hh[3] = {(const float*)d_in[5], (const float*)d_in[9],  (const float*)d_in[13]};
  const float* gw[4] = {(const float*)d_in[14], (const float*)d_in[16], (const float*)d_in[18], (const float*)d_in[20]};
  const float* gbv[4] = {(const float*)d_in[15], (const float*)d_in[17], (const float*)d_in[19], (const float*)d_in[21]};
  const float* fw1 = (const float*)d_in[22]; const float* fb1 = (const float*)d_in[23];
  const float* fw2 = (const float*)d_in[24]; const float* fb2 = (const float*)d_in[25];
  const float* fw3 = (const float*)d_in[26]; const float* fb3 = (const float*)d_in[27];
  const int* src = eidx;
  const int* dst = eidx + NEDGE;

  float* ws  = (float*)d_ws;
  float* xp  = ws;                      // 5,242,880 f
  float* hs0 = ws + 5242880;            // 1,310,720 f each
  float* hs1 = hs0 + 1310720;
  float* hs2 = hs1 + 1310720;
  unsigned int* deg = (unsigned int*)(hs2 + 1310720);
  float* dinv = (float*)(deg + 2048);
  float* emb  = dinv + 2048;
  float* ga = xp;
  float* gb = xp + 655360;
  float* x0 = xp + 1310720;
  float* x1 = xp + 1966080;

  hipMemsetAsync(hs0, 0x7F, (size_t)3 * 1310720 * sizeof(float), stream);
  hipMemsetAsync(deg, 0, 2048 * sizeof(unsigned int), stream);

  gemm_abt<<<dim3(GD / 64, NNODES / 64), 256, 0, stream>>>(
      x_in, w_ih[0], b_ih[0], b_hh[0], xp, NNODES, GD, KIN);

  deg_kernel<<<NEDGE / 256, 256, 0, stream>>>(dst, deg);
  dinv_kernel<<<NNODES / 256, 256, 0, stream>>>(deg, dinv);

  fused_scan<<<3 * SB, 256, 0, stream>>>(
      xp, w_hh[0], w_ih[1], w_hh[1], b_ih[1], b_hh[1],
      w_ih[2], w_hh[2], b_ih[2], b_hh[2], hs0, hs1, hs2);

  const int dims_in[4]  = {640, 320, 180, 90};
  const int dims_out[4] = {320, 180, 90, 50};
  const float* xin_l[4] = {hs2, x0, x1, x0};
  float* xout_l[4]      = {x0, x1, x0, x1};
  for (int l = 0; l < 4; l++) {
    gcn_gemm<<<NNODES, 256, 0, stream>>>(xin_l[l], gw[l], ga, dims_in[l], dims_out[l]);
    hipMemsetAsync(gb, 0, (size_t)NNODES * dims_out[l] * sizeof(float), stream);
    gcn_scatter<<<NEDGE, 128, 0, stream>>>(ga, src, dst, dinv, gb, dims_out[l]);
    gcn_bn<<<dims_out[l], 256, 0, stream>>>(gb, ga, dinv, gbv[l], xout_l[l], dims_out[l]);
  }

  pool_kernel<<<NGRAPH, 64, 0, stream>>>(x1, emb, (float*)d_out);
  fc_head<<<1, 64, 0, stream>>>(emb, fw1, fb1, fw2, fb2, fw3, fb3, (float*)d_out);
}